// Round 15
// baseline (188.853 us; speedup 1.0000x reference)
//
#include <hip/hip_runtime.h>
#include <hip/hip_bf16.h>
#include <hip/hip_fp16.h>
#include <cstdint>
#include <cstddef>

#define NB 8
#define TT 1024
#define DD 512
#define HH 8
#define DHD 64

using bf16x8 = __attribute__((ext_vector_type(8))) short;
using f32x4  = __attribute__((ext_vector_type(4))) float;
using s16x4  = __attribute__((ext_vector_type(4))) short;

#define MFMA(a, b, c) __builtin_amdgcn_mfma_f32_16x16x32_bf16((a), (b), (c), 0, 0, 0)

__device__ __forceinline__ short f2bf(float f) {
  union { float f; uint32_t u; } x; x.f = f;
  uint32_t r = x.u + 0x7fffu + ((x.u >> 16) & 1u);
  return (short)(r >> 16);
}

// pack two floats into two bf16 (round-nearest-even) in one u32
__device__ __forceinline__ uint32_t pkbf(float a, float b) {
  union { float f; uint32_t u; } x, y; x.f = a; y.f = b;
  uint32_t ra = x.u + 0x7fffu + ((x.u >> 16) & 1u);
  uint32_t rb = y.u + 0x7fffu + ((y.u >> 16) & 1u);
  return (ra >> 16) | (rb & 0xffff0000u);
}

// async global->LDS, 16B per lane; dst is wave-uniform base, lane l lands at dst + l*16B
__device__ __forceinline__ void gload_lds16(const short* src, short* dst) {
  __builtin_amdgcn_global_load_lds(
      (const __attribute__((address_space(1))) void*)src,
      (__attribute__((address_space(3))) void*)dst, 16, 0, 0);
}

// ---------------- weight transpose + f32->bf16 ----------------
__global__ __launch_bounds__(256) void kt_transpose(
    const float* __restrict__ W0, const float* __restrict__ W1,
    const float* __restrict__ W2, const float* __restrict__ W3,
    short* __restrict__ WT)
{
  __shared__ float tile[32][33];
  int z = blockIdx.z;
  const float* W = (z == 0) ? W0 : (z == 1) ? W1 : (z == 2) ? W2 : W3;
  short* out = WT + (size_t)z * DD * DD;
  int tx = threadIdx.x, ty = threadIdx.y;  // (32, 8)
  int bx = blockIdx.x * 32, by = blockIdx.y * 32;
#pragma unroll
  for (int kq = 0; kq < 4; ++kq)
    tile[ty + kq * 8][tx] = W[(size_t)(by + ty + kq * 8) * DD + bx + tx];
  __syncthreads();
#pragma unroll
  for (int kq = 0; kq < 4; ++kq)
    out[(size_t)(bx + ty + kq * 8) * DD + by + tx] = f2bf(tile[tx][ty + kq * 8]);
}

// ---------------- QKV projection GEMM, 128x128 tile ----------------
// z: 0=Q (scaled by 1/8, layout [N,H,T,64]), 1=K ([N,H,T,64]), 2=V ([N,H,64,T])
__global__ __launch_bounds__(256) void kt_proj(
    const float* __restrict__ Xq, const float* __restrict__ Xk, const float* __restrict__ Xv,
    const short* __restrict__ WTall,
    const float* __restrict__ bq, const float* __restrict__ bk, const float* __restrict__ bv,
    short* __restrict__ qb, short* __restrict__ kb, short* __restrict__ vT)
{
  int z = blockIdx.z;
  const float* X    = (z == 0) ? Xq : (z == 1) ? Xk : Xv;
  const short* WT   = WTall + (size_t)z * DD * DD;
  const float* bias = (z == 0) ? bq : (z == 1) ? bk : bv;
  short* out        = (z == 0) ? qb : (z == 1) ? kb : vT;

  __shared__ alignas(16) short As[128][40];
  __shared__ alignas(16) short Bs[128][40];
  int tid = threadIdx.x;
  int w = tid >> 6, lane = tid & 63, g = lane >> 4, c16 = lane & 15;
  int xb = blockIdx.x;
  int m0 = ((xb & 7) * 8 + (xb >> 3)) * 128;   // XCD-local batch mapping
  int c0 = blockIdx.y * 128;
  int wr = (w >> 1) * 64, wc = (w & 1) * 64;   // wave's output quadrant
  int srow = tid >> 1, shalf = (tid & 1) * 16;
  f32x4 acc[4][4] = {};

  for (int kk = 0; kk < DD; kk += 32) {
    {
      const float* ap = X + (size_t)(m0 + srow) * DD + kk + shalf;
      float4 a0 = *(const float4*)ap;
      float4 a1 = *(const float4*)(ap + 4);
      float4 a2 = *(const float4*)(ap + 8);
      float4 a3 = *(const float4*)(ap + 12);
      bf16x8 v0, v1;
      v0[0] = f2bf(a0.x); v0[1] = f2bf(a0.y); v0[2] = f2bf(a0.z); v0[3] = f2bf(a0.w);
      v0[4] = f2bf(a1.x); v0[5] = f2bf(a1.y); v0[6] = f2bf(a1.z); v0[7] = f2bf(a1.w);
      v1[0] = f2bf(a2.x); v1[1] = f2bf(a2.y); v1[2] = f2bf(a2.z); v1[3] = f2bf(a2.w);
      v1[4] = f2bf(a3.x); v1[5] = f2bf(a3.y); v1[6] = f2bf(a3.z); v1[7] = f2bf(a3.w);
      *(bf16x8*)&As[srow][shalf]     = v0;
      *(bf16x8*)&As[srow][shalf + 8] = v1;
    }
    {
      const short* bp = WT + (size_t)(c0 + srow) * DD + kk + shalf;
      *(bf16x8*)&Bs[srow][shalf]     = *(const bf16x8*)bp;
      *(bf16x8*)&Bs[srow][shalf + 8] = *(const bf16x8*)(bp + 8);
    }
    __syncthreads();
    bf16x8 af[4], bfv[4];
#pragma unroll
    for (int i = 0; i < 4; ++i) af[i]  = *(const bf16x8*)&As[wr + i * 16 + c16][g * 8];
#pragma unroll
    for (int j = 0; j < 4; ++j) bfv[j] = *(const bf16x8*)&Bs[wc + j * 16 + c16][g * 8];
#pragma unroll
    for (int i = 0; i < 4; ++i)
#pragma unroll
      for (int j = 0; j < 4; ++j)
        acc[i][j] = MFMA(af[i], bfv[j], acc[i][j]);
    __syncthreads();
  }

#pragma unroll
  for (int i = 0; i < 4; ++i)
#pragma unroll
    for (int j = 0; j < 4; ++j) {
      int c = c0 + wc + j * 16 + c16;
      float bv_ = bias[c];
      int hh = c >> 6, dh = c & 63;
#pragma unroll
      for (int r = 0; r < 4; ++r) {
        int m = m0 + wr + i * 16 + g * 4 + r;
        int n = m >> 10, t = m & 1023;
        float val = acc[i][j][r] + bv_;
        if (z == 0) val *= 0.125f;  // fold score scaling into q
        size_t addr = (z < 2)
            ? ((((size_t)n * HH + hh) * TT + t) * DHD + dh)     // q,k: [N,H,T,64]
            : ((((size_t)n * HH + hh) * DHD + dh) * TT + t);    // v : [N,H,64,T]
        out[addr] = f2bf(val);
      }
    }
}

// ---------------- output projection GEMM, 128x128 tile ----------------
__global__ __launch_bounds__(256) void kt_outproj(
    const short* __restrict__ A, const short* __restrict__ WT,
    const float* __restrict__ bias, float* __restrict__ out)
{
  __shared__ alignas(16) short As[128][40];
  __shared__ alignas(16) short Bs[128][40];
  int tid = threadIdx.x;
  int w = tid >> 6, lane = tid & 63, g = lane >> 4, c16 = lane & 15;
  int xb = blockIdx.x;
  int m0 = ((xb & 7) * 8 + (xb >> 3)) * 128;   // XCD-local batch mapping
  int c0 = blockIdx.y * 128;
  int wr = (w >> 1) * 64, wc = (w & 1) * 64;
  int srow = tid >> 1, shalf = (tid & 1) * 16;
  f32x4 acc[4][4] = {};

  for (int kk = 0; kk < DD; kk += 32) {
    {
      const short* ap = A + (size_t)(m0 + srow) * DD + kk + shalf;
      *(bf16x8*)&As[srow][shalf]     = *(const bf16x8*)ap;
      *(bf16x8*)&As[srow][shalf + 8] = *(const bf16x8*)(ap + 8);
      const short* bp = WT + (size_t)(c0 + srow) * DD + kk + shalf;
      *(bf16x8*)&Bs[srow][shalf]     = *(const bf16x8*)bp;
      *(bf16x8*)&Bs[srow][shalf + 8] = *(const bf16x8*)(bp + 8);
    }
    __syncthreads();
    bf16x8 af[4], bfv[4];
#pragma unroll
    for (int i = 0; i < 4; ++i) af[i]  = *(const bf16x8*)&As[wr + i * 16 + c16][g * 8];
#pragma unroll
    for (int j = 0; j < 4; ++j) bfv[j] = *(const bf16x8*)&Bs[wc + j * 16 + c16][g * 8];
#pragma unroll
    for (int i = 0; i < 4; ++i)
#pragma unroll
      for (int j = 0; j < 4; ++j)
        acc[i][j] = MFMA(af[i], bfv[j], acc[i][j]);
    __syncthreads();
  }

#pragma unroll
  for (int i = 0; i < 4; ++i)
#pragma unroll
    for (int j = 0; j < 4; ++j) {
      int c = c0 + wc + j * 16 + c16;
      float bv_ = bias[c];
#pragma unroll
      for (int r = 0; r < 4; ++r) {
        int m = m0 + wr + i * 16 + g * 4 + r;
        out[(size_t)m * DD + c] = acc[i][j][r] + bv_;
      }
    }
}

// ---------------- fused attention, v16 ----------------
// = v14 + extended async V staging: 11 of 16 V loads staged (ks0/ks1 full,
// ks2 partial ct0-2). LDS reclaimed from pads that v13 proved timing-neutral:
// pbuf [2][16][128], outw [2][16][64]. Total LDS 157696 B.
__global__ __launch_bounds__(512, 1) void kt_attn(
    const short* __restrict__ qbuf, const short* __restrict__ kbuf, const short* __restrict__ vT,
    const float* __restrict__ segms, const int* __restrict__ mask,
    short* __restrict__ attn, float* __restrict__ pmean)
{
  int bx = blockIdx.x;
  int n = bx & 7, qt = bx >> 3;          // qt 0..31; XCD-local batch
  int q0 = qt * 32;
  int tid = threadIdx.x, w = tid >> 6, lane = tid & 63, g = lane >> 4, c16 = lane & 15;
  int kw = w * 128;

  // per-wave union: pbuf short[2][16][128] (8192 B) | outw float[2][16][64] (8192 B)
  __shared__ alignas(16) char uni[8][8192];
  __shared__ alignas(16) float red_mT[32][8];
  __shared__ alignas(16) float red_sT[32][8];
  // wave-private V staging: ks0/ks1 full [64][32], ks2 partial [48][32]
  __shared__ alignas(16) short vstage[8][2][64][32];
  __shared__ alignas(16) short vstage2[8][48][32];
  short (*pbuf)[16][128] = (short (*)[16][128])uni[w];
  float (*outw)[16][64]  = (float (*)[16][64])uni[w];

  // ---- hoist mask bits + segms (fp16 packed); h-invariant; vectorized ----
  unsigned mmv[2];
  __half2 sgp[2][8][2];
  float pm[2][8][4];
  uint32_t rowbase[2];
#pragma unroll
  for (int s = 0; s < 2; ++s) {
    rowbase[s] = ((uint32_t)(n * TT) + q0 + s * 16 + c16) * TT + kw + g * 4;
    unsigned mm = 0u;
#pragma unroll
    for (int ct = 0; ct < 8; ++ct) {
      int4   mv = *(const int4*)  &mask [rowbase[s] + ct * 16];
      float4 sg = *(const float4*)&segms[rowbase[s] + ct * 16];
      if (mv.x) mm |= 1u << (ct * 4 + 0);
      if (mv.y) mm |= 1u << (ct * 4 + 1);
      if (mv.z) mm |= 1u << (ct * 4 + 2);
      if (mv.w) mm |= 1u << (ct * 4 + 3);
      sgp[s][ct][0] = __floats2half2_rn(sg.x, sg.y);
      sgp[s][ct][1] = __floats2half2_rn(sg.z, sg.w);
      pm[s][ct][0] = 0.f; pm[s][ct][1] = 0.f; pm[s][ct][2] = 0.f; pm[s][ct][3] = 0.f;
    }
    mmv[s] = mm;
  }

  for (int h = 0; h < HH; ++h) {
    const short* qp = qbuf + (((size_t)n * HH + h) * TT + q0) * DHD;
    const short* kp = kbuf + (((size_t)n * HH + h) * TT) * DHD;
    const short* vp = vT   + (((size_t)n * HH + h) * DHD) * TT;

    // ---- issue async V staging: ks0/ks1 full + ks2 rows 0-47 (zero VGPR) ----
    {
      int vr = lane >> 2, vcb = (lane & 3) * 8;
#pragma unroll
      for (int sl = 0; sl < 2; ++sl)
#pragma unroll
        for (int i = 0; i < 4; ++i)
          gload_lds16(vp + (size_t)(i * 16 + vr) * TT + kw + sl * 32 + vcb,
                      &vstage[w][sl][i * 16][0]);
#pragma unroll
      for (int i = 0; i < 3; ++i)
        gload_lds16(vp + (size_t)(i * 16 + vr) * TT + kw + 2 * 32 + vcb,
                    &vstage2[w][i * 16][0]);
    }

    bf16x8 aqA0 = *(const bf16x8*)(qp + c16 * DHD + g * 8);
    bf16x8 aqA1 = *(const bf16x8*)(qp + c16 * DHD + g * 8 + 32);
    bf16x8 aqB0 = *(const bf16x8*)(qp + (16 + c16) * DHD + g * 8);
    bf16x8 aqB1 = *(const bf16x8*)(qp + (16 + c16) * DHD + g * 8 + 32);

    // ---- swapped QK^T, both subtiles share each K fragment ----
    f32x4 scA[8], scB[8];
    __builtin_amdgcn_s_setprio(1);
#pragma unroll
    for (int ct = 0; ct < 8; ++ct) {
      const short* kpp = kp + (size_t)(kw + ct * 16 + c16) * DHD + g * 8;
      bf16x8 k0 = *(const bf16x8*)kpp;
      bf16x8 k1 = *(const bf16x8*)(kpp + 32);
      f32x4 a = {};
      a = MFMA(k0, aqA0, a);
      a = MFMA(k1, aqA1, a);
      scA[ct] = a;
      f32x4 b = {};
      b = MFMA(k0, aqB0, b);
      b = MFMA(k1, aqB1, b);
      scB[ct] = b;
    }
    __builtin_amdgcn_s_setprio(0);

    // ---- mask + in-lane row max + 2 shuffles (both subtiles) ----
    float mxA = -3e38f, mxB = -3e38f;
#pragma unroll
    for (int ct = 0; ct < 8; ++ct)
#pragma unroll
      for (int r = 0; r < 4; ++r) {
        float sa = ((mmv[0] >> (ct * 4 + r)) & 1u) ? scA[ct][r] : -1e9f;
        float sb = ((mmv[1] >> (ct * 4 + r)) & 1u) ? scB[ct][r] : -1e9f;
        scA[ct][r] = sa; scB[ct][r] = sb;
        mxA = fmaxf(mxA, sa); mxB = fmaxf(mxB, sb);
      }
    mxA = fmaxf(mxA, __shfl_xor(mxA, 16));
    mxA = fmaxf(mxA, __shfl_xor(mxA, 32));
    mxB = fmaxf(mxB, __shfl_xor(mxB, 16));
    mxB = fmaxf(mxB, __shfl_xor(mxB, 32));

    // ---- exp with wave-local max (p<=1 safe) + in-lane sum + 2 shuffles ----
    float smA = 0.f, smB = 0.f;
#pragma unroll
    for (int ct = 0; ct < 8; ++ct)
#pragma unroll
      for (int r = 0; r < 4; ++r) {
        float pa = __expf(scA[ct][r] - mxA);
        float pb = __expf(scB[ct][r] - mxB);
        scA[ct][r] = pa; scB[ct][r] = pb;
        smA += pa; smB += pb;
      }
    smA += __shfl_xor(smA, 16);
    smA += __shfl_xor(smA, 32);
    smB += __shfl_xor(smB, 16);
    smB += __shfl_xor(smB, 32);
    if (lane < 16) {
      red_mT[c16][w] = mxA;      red_sT[c16][w] = smA;
      red_mT[16 + c16][w] = mxB; red_sT[16 + c16][w] = smB;
    }
    __syncthreads();  // barrier A: (m,S) ready; fences prev head's outw reads vs pbuf writes

    // ---- combine for q=c16 (A) and q=16+c16 (B) ----
    float sclA, sclB;
    {
      f32x4 vm0 = *(const f32x4*)&red_mT[c16][0];
      f32x4 vm1 = *(const f32x4*)&red_mT[c16][4];
      f32x4 vs0 = *(const f32x4*)&red_sT[c16][0];
      f32x4 vs1 = *(const f32x4*)&red_sT[c16][4];
      float ms = fmaxf(fmaxf(fmaxf(vm0[0], vm0[1]), fmaxf(vm0[2], vm0[3])),
                       fmaxf(fmaxf(vm1[0], vm1[1]), fmaxf(vm1[2], vm1[3])));
      float Z = vs0[0] * __expf(vm0[0] - ms) + vs0[1] * __expf(vm0[1] - ms)
              + vs0[2] * __expf(vm0[2] - ms) + vs0[3] * __expf(vm0[3] - ms)
              + vs1[0] * __expf(vm1[0] - ms) + vs1[1] * __expf(vm1[1] - ms)
              + vs1[2] * __expf(vm1[2] - ms) + vs1[3] * __expf(vm1[3] - ms);
      sclA = __expf(mxA - ms) / Z;
    }
    {
      f32x4 vm0 = *(const f32x4*)&red_mT[16 + c16][0];
      f32x4 vm1 = *(const f32x4*)&red_mT[16 + c16][4];
      f32x4 vs0 = *(const f32x4*)&red_sT[16 + c16][0];
      f32x4 vs1 = *(const f32x4*)&red_sT[16 + c16][4];
      float ms = fmaxf(fmaxf(fmaxf(vm0[0], vm0[1]), fmaxf(vm0[2], vm0[3])),
                       fmaxf(fmaxf(vm1[0], vm1[1]), fmaxf(vm1[2], vm1[3])));
      float Z = vs0[0] * __expf(vm0[0] - ms) + vs0[1] * __expf(vm0[1] - ms)
              + vs0[2] * __expf(vm0[2] - ms) + vs0[3] * __expf(vm0[3] - ms)
              + vs1[0] * __expf(vm1[0] - ms) + vs1[1] * __expf(vm1[1] - ms)
              + vs1[2] * __expf(vm1[2] - ms) + vs1[3] * __expf(vm1[3] - ms);
      sclB = __expf(mxB - ms) / Z;
    }

    // ---- probs = p*scale*segms ; accumulate pmean ; stash packed b64 ----
#pragma unroll
    for (int ct = 0; ct < 8; ++ct) {
      {
        float2 s01 = __half22float2(sgp[0][ct][0]);
        float2 s23 = __half22float2(sgp[0][ct][1]);
        float p0 = scA[ct][0] * sclA * s01.x;
        float p1 = scA[ct][1] * sclA * s01.y;
        float p2 = scA[ct][2] * sclA * s23.x;
        float p3 = scA[ct][3] * sclA * s23.y;
        pm[0][ct][0] += p0; pm[0][ct][1] += p1; pm[0][ct][2] += p2; pm[0][ct][3] += p3;
        uint2 pk; pk.x = pkbf(p0, p1); pk.y = pkbf(p2, p3);
        *(uint2*)&pbuf[0][c16][ct * 16 + g * 4] = pk;
      }
      {
        float2 s01 = __half22float2(sgp[1][ct][0]);
        float2 s23 = __half22float2(sgp[1][ct][1]);
        float p0 = scB[ct][0] * sclB * s01.x;
        float p1 = scB[ct][1] * sclB * s01.y;
        float p2 = scB[ct][2] * sclB * s23.x;
        float p3 = scB[ct][3] * sclB * s23.y;
        pm[1][ct][0] += p0; pm[1][ct][1] += p1; pm[1][ct][2] += p2; pm[1][ct][3] += p3;
        uint2 pk; pk.x = pkbf(p0, p1); pk.y = pkbf(p2, p3);
        *(uint2*)&pbuf[1][c16][ct * 16 + g * 4] = pk;
      }
    }
    // no barrier: pbuf slice is wave-private (same-wave ds ordering)

    // ---- drain V staging (long since complete) before LDS reads ----
    asm volatile("s_waitcnt vmcnt(0)" ::: "memory");
    __builtin_amdgcn_sched_barrier(0);

    // ---- PV subtile A (ks0/ks1 + ks2/ct<3 from LDS; rest direct) ----
    {
      f32x4 oa[4] = {};
      __builtin_amdgcn_s_setprio(1);
#pragma unroll
      for (int ks = 0; ks < 4; ++ks) {
        bf16x8 pa = *(const bf16x8*)&pbuf[0][c16][ks * 32 + g * 8];
#pragma unroll
        for (int ct = 0; ct < 4; ++ct) {
          bf16x8 bv;
          if (ks < 2)                 bv = *(const bf16x8*)&vstage[w][ks][ct * 16 + c16][g * 8];
          else if (ks == 2 && ct < 3) bv = *(const bf16x8*)&vstage2[w][ct * 16 + c16][g * 8];
          else                        bv = *(const bf16x8*)(vp + (size_t)(ct * 16 + c16) * TT + kw + ks * 32 + g * 8);
          oa[ct] = MFMA(pa, bv, oa[ct]);
        }
      }
      __builtin_amdgcn_s_setprio(0);
#pragma unroll
      for (int ct = 0; ct < 4; ++ct)
#pragma unroll
        for (int r = 0; r < 4; ++r)
          outw[0][g * 4 + r][ct * 16 + c16] = oa[ct][r];
    }
    // ---- PV subtile B ----
    {
      f32x4 ob[4] = {};
      __builtin_amdgcn_s_setprio(1);
#pragma unroll
      for (int ks = 0; ks < 4; ++ks) {
        bf16x8 pa = *(const bf16x8*)&pbuf[1][c16][ks * 32 + g * 8];
#pragma unroll
        for (int ct = 0; ct < 4; ++ct) {
          bf16x8 bv;
          if (ks < 2)                 bv = *(const bf16x8*)&vstage[w][ks][ct * 16 + c16][g * 8];
          else if (ks == 2 && ct < 3) bv = *(const bf16x8*)&vstage2[w][ct * 16 + c16][g * 8];
          else                        bv = *(const bf16x8*)(vp + (size_t)(ct * 16 + c16) * TT + kw + ks * 32 + g * 8);
          ob[ct] = MFMA(pa, bv, ob[ct]);
        }
      }
      __builtin_amdgcn_s_setprio(0);
#pragma unroll
      for (int ct = 0; ct < 4; ++ct)
#pragma unroll
        for (int r = 0; r < 4; ++r)
          outw[1][g * 4 + r][ct * 16 + c16] = ob[ct][r];
    }
    __syncthreads();  // barrier C: all partials ready

    // ---- cross-wave reduce (8 partials, 32 q-rows) + write attn ----
    {
      int q = tid >> 4, dg = (tid & 15) * 4;
      int s = q >> 4, qr = q & 15;
      float v0 = 0.f, v1 = 0.f, v2 = 0.f, v3 = 0.f;
#pragma unroll
      for (int wi = 0; wi < 8; ++wi) {
        const float* op = (const float*)uni[wi] + (size_t)s * 16 * 64 + qr * 64 + dg;
        float4 rd = *(const float4*)op;
        v0 += rd.x; v1 += rd.y; v2 += rd.z; v3 += rd.w;
      }
      s16x4 st;
      st[0] = f2bf(v0); st[1] = f2bf(v1); st[2] = f2bf(v2); st[3] = f2bf(v3);
      *(s16x4*)(attn + ((size_t)(n * TT) + q0 + q) * DD + h * DHD + dg) = st;
    }
    // next head's pbuf writes are fenced by barrier A of that head
  }

  // ---- write probs mean (1/H), vectorized float4 ----
#pragma unroll
  for (int s = 0; s < 2; ++s)
#pragma unroll
    for (int ct = 0; ct < 8; ++ct) {
      float4 o;
      o.x = pm[s][ct][0] * 0.125f; o.y = pm[s][ct][1] * 0.125f;
      o.z = pm[s][ct][2] * 0.125f; o.w = pm[s][ct][3] * 0.125f;
      *(float4*)&pmean[rowbase[s] + ct * 16] = o;
    }
}

extern "C" void kernel_launch(void* const* d_in, const int* in_sizes, int n_in,
                              void* d_out, int out_size, void* d_ws, size_t ws_size,
                              hipStream_t stream) {
  const float* query = (const float*)d_in[0];
  const float* key_  = (const float*)d_in[1];
  const float* value = (const float*)d_in[2];
  const float* segms = (const float*)d_in[3];
  const int*   mask  = (const int*)d_in[4];
  const float* Wq = (const float*)d_in[5];
  const float* bq = (const float*)d_in[6];
  const float* Wk = (const float*)d_in[7];
  const float* bk = (const float*)d_in[8];
  const float* Wv = (const float*)d_in[9];
  const float* bv = (const float*)d_in[10];
  const float* Wo = (const float*)d_in[11];
  const float* bo = (const float*)d_in[12];

  char* ws = (char*)d_ws;
  short* WT   = (short*)(ws);                        // 4 x 512x512 bf16 = 2 MB
  short* qb   = (short*)(ws + ((size_t)2  << 20));   // [N,H,T,64] bf16 = 8 MB
  short* kb   = (short*)(ws + ((size_t)10 << 20));   // [N,H,T,64] bf16 = 8 MB
  short* vT   = (short*)(ws + ((size_t)18 << 20));   // [N,H,64,T] bf16 = 8 MB
  short* attn = (short*)(ws + ((size_t)26 << 20));   // [N,T,D]   bf16 = 8 MB
  float* outp  = (float*)d_out;
  float* pmean = outp + (size_t)NB * TT * DD;

  kt_transpose<<<dim3(16, 16, 4), dim3(32, 8), 0, stream>>>(Wq, Wk, Wv, Wo, WT);
  kt_proj<<<dim3(64, 4, 3), 256, 0, stream>>>(query, key_, value, WT, bq, bk, bv, qb, kb, vT);
  kt_attn<<<dim3(256), dim3(512), 0, stream>>>(qb, kb, vT, segms, mask, attn, pmean);
  kt_outproj<<<dim3(64, 4), 256, 0, stream>>>(attn, WT + (size_t)3 * DD * DD, bo, outp);
}

// Round 16
// 175.568 us; speedup vs baseline: 1.0757x; 1.0757x over previous
//
#include <hip/hip_runtime.h>
#include <hip/hip_bf16.h>
#include <hip/hip_fp16.h>
#include <cstdint>
#include <cstddef>

#define NB 8
#define TT 1024
#define DD 512
#define HH 8
#define DHD 64

using bf16x8 = __attribute__((ext_vector_type(8))) short;
using f32x4  = __attribute__((ext_vector_type(4))) float;
using s16x4  = __attribute__((ext_vector_type(4))) short;

#define MFMA(a, b, c) __builtin_amdgcn_mfma_f32_16x16x32_bf16((a), (b), (c), 0, 0, 0)

__device__ __forceinline__ short f2bf(float f) {
  union { float f; uint32_t u; } x; x.f = f;
  uint32_t r = x.u + 0x7fffu + ((x.u >> 16) & 1u);
  return (short)(r >> 16);
}

// pack two floats into two bf16 (round-nearest-even) in one u32
__device__ __forceinline__ uint32_t pkbf(float a, float b) {
  union { float f; uint32_t u; } x, y; x.f = a; y.f = b;
  uint32_t ra = x.u + 0x7fffu + ((x.u >> 16) & 1u);
  uint32_t rb = y.u + 0x7fffu + ((y.u >> 16) & 1u);
  return (ra >> 16) | (rb & 0xffff0000u);
}

// async global->LDS, 16B per lane; dst is wave-uniform base, lane l lands at dst + l*16B
__device__ __forceinline__ void gload_lds16(const short* src, short* dst) {
  __builtin_amdgcn_global_load_lds(
      (const __attribute__((address_space(1))) void*)src,
      (__attribute__((address_space(3))) void*)dst, 16, 0, 0);
}

// ---------------- weight transpose + f32->bf16 ----------------
__global__ __launch_bounds__(256) void kt_transpose(
    const float* __restrict__ W0, const float* __restrict__ W1,
    const float* __restrict__ W2, const float* __restrict__ W3,
    short* __restrict__ WT)
{
  __shared__ float tile[32][33];
  int z = blockIdx.z;
  const float* W = (z == 0) ? W0 : (z == 1) ? W1 : (z == 2) ? W2 : W3;
  short* out = WT + (size_t)z * DD * DD;
  int tx = threadIdx.x, ty = threadIdx.y;  // (32, 8)
  int bx = blockIdx.x * 32, by = blockIdx.y * 32;
#pragma unroll
  for (int kq = 0; kq < 4; ++kq)
    tile[ty + kq * 8][tx] = W[(size_t)(by + ty + kq * 8) * DD + bx + tx];
  __syncthreads();
#pragma unroll
  for (int kq = 0; kq < 4; ++kq)
    out[(size_t)(bx + ty + kq * 8) * DD + by + tx] = f2bf(tile[tx][ty + kq * 8]);
}

// ---------------- QKV projection GEMM, 128x128 tile ----------------
// z: 0=Q (scaled by 1/8, layout [N,H,T,64]), 1=K ([N,H,T,64]), 2=V ([N,H,64,T])
__global__ __launch_bounds__(256) void kt_proj(
    const float* __restrict__ Xq, const float* __restrict__ Xk, const float* __restrict__ Xv,
    const short* __restrict__ WTall,
    const float* __restrict__ bq, const float* __restrict__ bk, const float* __restrict__ bv,
    short* __restrict__ qb, short* __restrict__ kb, short* __restrict__ vT)
{
  int z = blockIdx.z;
  const float* X    = (z == 0) ? Xq : (z == 1) ? Xk : Xv;
  const short* WT   = WTall + (size_t)z * DD * DD;
  const float* bias = (z == 0) ? bq : (z == 1) ? bk : bv;
  short* out        = (z == 0) ? qb : (z == 1) ? kb : vT;

  __shared__ alignas(16) short As[128][40];
  __shared__ alignas(16) short Bs[128][40];
  int tid = threadIdx.x;
  int w = tid >> 6, lane = tid & 63, g = lane >> 4, c16 = lane & 15;
  int xb = blockIdx.x;
  int m0 = ((xb & 7) * 8 + (xb >> 3)) * 128;   // XCD-local batch mapping
  int c0 = blockIdx.y * 128;
  int wr = (w >> 1) * 64, wc = (w & 1) * 64;   // wave's output quadrant
  int srow = tid >> 1, shalf = (tid & 1) * 16;
  f32x4 acc[4][4] = {};

  for (int kk = 0; kk < DD; kk += 32) {
    {
      const float* ap = X + (size_t)(m0 + srow) * DD + kk + shalf;
      float4 a0 = *(const float4*)ap;
      float4 a1 = *(const float4*)(ap + 4);
      float4 a2 = *(const float4*)(ap + 8);
      float4 a3 = *(const float4*)(ap + 12);
      bf16x8 v0, v1;
      v0[0] = f2bf(a0.x); v0[1] = f2bf(a0.y); v0[2] = f2bf(a0.z); v0[3] = f2bf(a0.w);
      v0[4] = f2bf(a1.x); v0[5] = f2bf(a1.y); v0[6] = f2bf(a1.z); v0[7] = f2bf(a1.w);
      v1[0] = f2bf(a2.x); v1[1] = f2bf(a2.y); v1[2] = f2bf(a2.z); v1[3] = f2bf(a2.w);
      v1[4] = f2bf(a3.x); v1[5] = f2bf(a3.y); v1[6] = f2bf(a3.z); v1[7] = f2bf(a3.w);
      *(bf16x8*)&As[srow][shalf]     = v0;
      *(bf16x8*)&As[srow][shalf + 8] = v1;
    }
    {
      const short* bp = WT + (size_t)(c0 + srow) * DD + kk + shalf;
      *(bf16x8*)&Bs[srow][shalf]     = *(const bf16x8*)bp;
      *(bf16x8*)&Bs[srow][shalf + 8] = *(const bf16x8*)(bp + 8);
    }
    __syncthreads();
    bf16x8 af[4], bfv[4];
#pragma unroll
    for (int i = 0; i < 4; ++i) af[i]  = *(const bf16x8*)&As[wr + i * 16 + c16][g * 8];
#pragma unroll
    for (int j = 0; j < 4; ++j) bfv[j] = *(const bf16x8*)&Bs[wc + j * 16 + c16][g * 8];
#pragma unroll
    for (int i = 0; i < 4; ++i)
#pragma unroll
      for (int j = 0; j < 4; ++j)
        acc[i][j] = MFMA(af[i], bfv[j], acc[i][j]);
    __syncthreads();
  }

#pragma unroll
  for (int i = 0; i < 4; ++i)
#pragma unroll
    for (int j = 0; j < 4; ++j) {
      int c = c0 + wc + j * 16 + c16;
      float bv_ = bias[c];
      int hh = c >> 6, dh = c & 63;
#pragma unroll
      for (int r = 0; r < 4; ++r) {
        int m = m0 + wr + i * 16 + g * 4 + r;
        int n = m >> 10, t = m & 1023;
        float val = acc[i][j][r] + bv_;
        if (z == 0) val *= 0.125f;  // fold score scaling into q
        size_t addr = (z < 2)
            ? ((((size_t)n * HH + hh) * TT + t) * DHD + dh)     // q,k: [N,H,T,64]
            : ((((size_t)n * HH + hh) * DHD + dh) * TT + t);    // v : [N,H,64,T]
        out[addr] = f2bf(val);
      }
    }
}

// ---------------- output projection GEMM, 128x128 tile ----------------
__global__ __launch_bounds__(256) void kt_outproj(
    const short* __restrict__ A, const short* __restrict__ WT,
    const float* __restrict__ bias, float* __restrict__ out)
{
  __shared__ alignas(16) short As[128][40];
  __shared__ alignas(16) short Bs[128][40];
  int tid = threadIdx.x;
  int w = tid >> 6, lane = tid & 63, g = lane >> 4, c16 = lane & 15;
  int xb = blockIdx.x;
  int m0 = ((xb & 7) * 8 + (xb >> 3)) * 128;   // XCD-local batch mapping
  int c0 = blockIdx.y * 128;
  int wr = (w >> 1) * 64, wc = (w & 1) * 64;
  int srow = tid >> 1, shalf = (tid & 1) * 16;
  f32x4 acc[4][4] = {};

  for (int kk = 0; kk < DD; kk += 32) {
    {
      const short* ap = A + (size_t)(m0 + srow) * DD + kk + shalf;
      *(bf16x8*)&As[srow][shalf]     = *(const bf16x8*)ap;
      *(bf16x8*)&As[srow][shalf + 8] = *(const bf16x8*)(ap + 8);
      const short* bp = WT + (size_t)(c0 + srow) * DD + kk + shalf;
      *(bf16x8*)&Bs[srow][shalf]     = *(const bf16x8*)bp;
      *(bf16x8*)&Bs[srow][shalf + 8] = *(const bf16x8*)(bp + 8);
    }
    __syncthreads();
    bf16x8 af[4], bfv[4];
#pragma unroll
    for (int i = 0; i < 4; ++i) af[i]  = *(const bf16x8*)&As[wr + i * 16 + c16][g * 8];
#pragma unroll
    for (int j = 0; j < 4; ++j) bfv[j] = *(const bf16x8*)&Bs[wc + j * 16 + c16][g * 8];
#pragma unroll
    for (int i = 0; i < 4; ++i)
#pragma unroll
      for (int j = 0; j < 4; ++j)
        acc[i][j] = MFMA(af[i], bfv[j], acc[i][j]);
    __syncthreads();
  }

#pragma unroll
  for (int i = 0; i < 4; ++i)
#pragma unroll
    for (int j = 0; j < 4; ++j) {
      int c = c0 + wc + j * 16 + c16;
      float bv_ = bias[c];
#pragma unroll
      for (int r = 0; r < 4; ++r) {
        int m = m0 + wr + i * 16 + g * 4 + r;
        out[(size_t)m * DD + c] = acc[i][j][r] + bv_;
      }
    }
}

// ---------------- fused attention, v17 ----------------
// = v15's attn (v14: padded pbuf [2][16][132] / outw [2][16][66] -- the pads
// are REQUIRED: v16's unpadded strides caused 22.6M bank conflicts, +11us)
// + vstage2 [16][32] for ks2/ct0 (9 of 16 V loads async). LDS 143360 B.
__global__ __launch_bounds__(512, 1) void kt_attn(
    const short* __restrict__ qbuf, const short* __restrict__ kbuf, const short* __restrict__ vT,
    const float* __restrict__ segms, const int* __restrict__ mask,
    short* __restrict__ attn, float* __restrict__ pmean)
{
  int bx = blockIdx.x;
  int n = bx & 7, qt = bx >> 3;          // qt 0..31; XCD-local batch
  int q0 = qt * 32;
  int tid = threadIdx.x, w = tid >> 6, lane = tid & 63, g = lane >> 4, c16 = lane & 15;
  int kw = w * 128;

  // per-wave union: pbuf short[2][16][132] (8448 B) | outw float[2][16][66] (8448 B)
  __shared__ alignas(16) char uni[8][8448];
  __shared__ alignas(16) float red_mT[32][8];
  __shared__ alignas(16) float red_sT[32][8];
  // wave-private V staging: ks0/ks1 full [64][32], ks2 ct0 [16][32]
  __shared__ alignas(16) short vstage[8][2][64][32];
  __shared__ alignas(16) short vstage2[8][16][32];
  short (*pbuf)[16][132] = (short (*)[16][132])uni[w];
  float (*outw)[16][66]  = (float (*)[16][66])uni[w];

  // ---- hoist mask bits + segms (fp16 packed); h-invariant; vectorized ----
  unsigned mmv[2];
  __half2 sgp[2][8][2];
  float pm[2][8][4];
  uint32_t rowbase[2];
#pragma unroll
  for (int s = 0; s < 2; ++s) {
    rowbase[s] = ((uint32_t)(n * TT) + q0 + s * 16 + c16) * TT + kw + g * 4;
    unsigned mm = 0u;
#pragma unroll
    for (int ct = 0; ct < 8; ++ct) {
      int4   mv = *(const int4*)  &mask [rowbase[s] + ct * 16];
      float4 sg = *(const float4*)&segms[rowbase[s] + ct * 16];
      if (mv.x) mm |= 1u << (ct * 4 + 0);
      if (mv.y) mm |= 1u << (ct * 4 + 1);
      if (mv.z) mm |= 1u << (ct * 4 + 2);
      if (mv.w) mm |= 1u << (ct * 4 + 3);
      sgp[s][ct][0] = __floats2half2_rn(sg.x, sg.y);
      sgp[s][ct][1] = __floats2half2_rn(sg.z, sg.w);
      pm[s][ct][0] = 0.f; pm[s][ct][1] = 0.f; pm[s][ct][2] = 0.f; pm[s][ct][3] = 0.f;
    }
    mmv[s] = mm;
  }

  for (int h = 0; h < HH; ++h) {
    const short* qp = qbuf + (((size_t)n * HH + h) * TT + q0) * DHD;
    const short* kp = kbuf + (((size_t)n * HH + h) * TT) * DHD;
    const short* vp = vT   + (((size_t)n * HH + h) * DHD) * TT;

    // ---- issue async V staging: ks0/ks1 full + ks2 ct0 (zero VGPR cost) ----
    {
      int vr = lane >> 2, vcb = (lane & 3) * 8;
#pragma unroll
      for (int sl = 0; sl < 2; ++sl)
#pragma unroll
        for (int i = 0; i < 4; ++i)
          gload_lds16(vp + (size_t)(i * 16 + vr) * TT + kw + sl * 32 + vcb,
                      &vstage[w][sl][i * 16][0]);
      gload_lds16(vp + (size_t)vr * TT + kw + 2 * 32 + vcb, &vstage2[w][0][0]);
    }

    bf16x8 aqA0 = *(const bf16x8*)(qp + c16 * DHD + g * 8);
    bf16x8 aqA1 = *(const bf16x8*)(qp + c16 * DHD + g * 8 + 32);
    bf16x8 aqB0 = *(const bf16x8*)(qp + (16 + c16) * DHD + g * 8);
    bf16x8 aqB1 = *(const bf16x8*)(qp + (16 + c16) * DHD + g * 8 + 32);

    // ---- swapped QK^T, both subtiles share each K fragment ----
    f32x4 scA[8], scB[8];
    __builtin_amdgcn_s_setprio(1);
#pragma unroll
    for (int ct = 0; ct < 8; ++ct) {
      const short* kpp = kp + (size_t)(kw + ct * 16 + c16) * DHD + g * 8;
      bf16x8 k0 = *(const bf16x8*)kpp;
      bf16x8 k1 = *(const bf16x8*)(kpp + 32);
      f32x4 a = {};
      a = MFMA(k0, aqA0, a);
      a = MFMA(k1, aqA1, a);
      scA[ct] = a;
      f32x4 b = {};
      b = MFMA(k0, aqB0, b);
      b = MFMA(k1, aqB1, b);
      scB[ct] = b;
    }
    __builtin_amdgcn_s_setprio(0);

    // ---- mask + in-lane row max + 2 shuffles (both subtiles) ----
    float mxA = -3e38f, mxB = -3e38f;
#pragma unroll
    for (int ct = 0; ct < 8; ++ct)
#pragma unroll
      for (int r = 0; r < 4; ++r) {
        float sa = ((mmv[0] >> (ct * 4 + r)) & 1u) ? scA[ct][r] : -1e9f;
        float sb = ((mmv[1] >> (ct * 4 + r)) & 1u) ? scB[ct][r] : -1e9f;
        scA[ct][r] = sa; scB[ct][r] = sb;
        mxA = fmaxf(mxA, sa); mxB = fmaxf(mxB, sb);
      }
    mxA = fmaxf(mxA, __shfl_xor(mxA, 16));
    mxA = fmaxf(mxA, __shfl_xor(mxA, 32));
    mxB = fmaxf(mxB, __shfl_xor(mxB, 16));
    mxB = fmaxf(mxB, __shfl_xor(mxB, 32));

    // ---- exp with wave-local max (p<=1 safe) + in-lane sum + 2 shuffles ----
    float smA = 0.f, smB = 0.f;
#pragma unroll
    for (int ct = 0; ct < 8; ++ct)
#pragma unroll
      for (int r = 0; r < 4; ++r) {
        float pa = __expf(scA[ct][r] - mxA);
        float pb = __expf(scB[ct][r] - mxB);
        scA[ct][r] = pa; scB[ct][r] = pb;
        smA += pa; smB += pb;
      }
    smA += __shfl_xor(smA, 16);
    smA += __shfl_xor(smA, 32);
    smB += __shfl_xor(smB, 16);
    smB += __shfl_xor(smB, 32);
    if (lane < 16) {
      red_mT[c16][w] = mxA;      red_sT[c16][w] = smA;
      red_mT[16 + c16][w] = mxB; red_sT[16 + c16][w] = smB;
    }
    __syncthreads();  // barrier A: (m,S) ready; fences prev head's outw reads vs pbuf writes

    // ---- combine for q=c16 (A) and q=16+c16 (B) ----
    float sclA, sclB;
    {
      f32x4 vm0 = *(const f32x4*)&red_mT[c16][0];
      f32x4 vm1 = *(const f32x4*)&red_mT[c16][4];
      f32x4 vs0 = *(const f32x4*)&red_sT[c16][0];
      f32x4 vs1 = *(const f32x4*)&red_sT[c16][4];
      float ms = fmaxf(fmaxf(fmaxf(vm0[0], vm0[1]), fmaxf(vm0[2], vm0[3])),
                       fmaxf(fmaxf(vm1[0], vm1[1]), fmaxf(vm1[2], vm1[3])));
      float Z = vs0[0] * __expf(vm0[0] - ms) + vs0[1] * __expf(vm0[1] - ms)
              + vs0[2] * __expf(vm0[2] - ms) + vs0[3] * __expf(vm0[3] - ms)
              + vs1[0] * __expf(vm1[0] - ms) + vs1[1] * __expf(vm1[1] - ms)
              + vs1[2] * __expf(vm1[2] - ms) + vs1[3] * __expf(vm1[3] - ms);
      sclA = __expf(mxA - ms) / Z;
    }
    {
      f32x4 vm0 = *(const f32x4*)&red_mT[16 + c16][0];
      f32x4 vm1 = *(const f32x4*)&red_mT[16 + c16][4];
      f32x4 vs0 = *(const f32x4*)&red_sT[16 + c16][0];
      f32x4 vs1 = *(const f32x4*)&red_sT[16 + c16][4];
      float ms = fmaxf(fmaxf(fmaxf(vm0[0], vm0[1]), fmaxf(vm0[2], vm0[3])),
                       fmaxf(fmaxf(vm1[0], vm1[1]), fmaxf(vm1[2], vm1[3])));
      float Z = vs0[0] * __expf(vm0[0] - ms) + vs0[1] * __expf(vm0[1] - ms)
              + vs0[2] * __expf(vm0[2] - ms) + vs0[3] * __expf(vm0[3] - ms)
              + vs1[0] * __expf(vm1[0] - ms) + vs1[1] * __expf(vm1[1] - ms)
              + vs1[2] * __expf(vm1[2] - ms) + vs1[3] * __expf(vm1[3] - ms);
      sclB = __expf(mxB - ms) / Z;
    }

    // ---- probs = p*scale*segms ; accumulate pmean ; stash packed b64 ----
#pragma unroll
    for (int ct = 0; ct < 8; ++ct) {
      {
        float2 s01 = __half22float2(sgp[0][ct][0]);
        float2 s23 = __half22float2(sgp[0][ct][1]);
        float p0 = scA[ct][0] * sclA * s01.x;
        float p1 = scA[ct][1] * sclA * s01.y;
        float p2 = scA[ct][2] * sclA * s23.x;
        float p3 = scA[ct][3] * sclA * s23.y;
        pm[0][ct][0] += p0; pm[0][ct][1] += p1; pm[0][ct][2] += p2; pm[0][ct][3] += p3;
        uint2 pk; pk.x = pkbf(p0, p1); pk.y = pkbf(p2, p3);
        *(uint2*)&pbuf[0][c16][ct * 16 + g * 4] = pk;
      }
      {
        float2 s01 = __half22float2(sgp[1][ct][0]);
        float2 s23 = __half22float2(sgp[1][ct][1]);
        float p0 = scB[ct][0] * sclB * s01.x;
        float p1 = scB[ct][1] * sclB * s01.y;
        float p2 = scB[ct][2] * sclB * s23.x;
        float p3 = scB[ct][3] * sclB * s23.y;
        pm[1][ct][0] += p0; pm[1][ct][1] += p1; pm[1][ct][2] += p2; pm[1][ct][3] += p3;
        uint2 pk; pk.x = pkbf(p0, p1); pk.y = pkbf(p2, p3);
        *(uint2*)&pbuf[1][c16][ct * 16 + g * 4] = pk;
      }
    }
    // no barrier: pbuf slice is wave-private (same-wave ds ordering)

    // ---- drain V staging (long since complete) before LDS reads ----
    asm volatile("s_waitcnt vmcnt(0)" ::: "memory");
    __builtin_amdgcn_sched_barrier(0);

    // ---- PV subtile A (ks0/ks1 + ks2/ct0 from LDS; rest direct) ----
    {
      f32x4 oa[4] = {};
      __builtin_amdgcn_s_setprio(1);
#pragma unroll
      for (int ks = 0; ks < 4; ++ks) {
        bf16x8 pa = *(const bf16x8*)&pbuf[0][c16][ks * 32 + g * 8];
#pragma unroll
        for (int ct = 0; ct < 4; ++ct) {
          bf16x8 bv;
          if (ks < 2)                  bv = *(const bf16x8*)&vstage[w][ks][ct * 16 + c16][g * 8];
          else if (ks == 2 && ct == 0) bv = *(const bf16x8*)&vstage2[w][c16][g * 8];
          else                         bv = *(const bf16x8*)(vp + (size_t)(ct * 16 + c16) * TT + kw + ks * 32 + g * 8);
          oa[ct] = MFMA(pa, bv, oa[ct]);
        }
      }
      __builtin_amdgcn_s_setprio(0);
#pragma unroll
      for (int ct = 0; ct < 4; ++ct)
#pragma unroll
        for (int r = 0; r < 4; ++r)
          outw[0][g * 4 + r][ct * 16 + c16] = oa[ct][r];
    }
    // ---- PV subtile B ----
    {
      f32x4 ob[4] = {};
      __builtin_amdgcn_s_setprio(1);
#pragma unroll
      for (int ks = 0; ks < 4; ++ks) {
        bf16x8 pa = *(const bf16x8*)&pbuf[1][c16][ks * 32 + g * 8];
#pragma unroll
        for (int ct = 0; ct < 4; ++ct) {
          bf16x8 bv;
          if (ks < 2)                  bv = *(const bf16x8*)&vstage[w][ks][ct * 16 + c16][g * 8];
          else if (ks == 2 && ct == 0) bv = *(const bf16x8*)&vstage2[w][c16][g * 8];
          else                         bv = *(const bf16x8*)(vp + (size_t)(ct * 16 + c16) * TT + kw + ks * 32 + g * 8);
          ob[ct] = MFMA(pa, bv, ob[ct]);
        }
      }
      __builtin_amdgcn_s_setprio(0);
#pragma unroll
      for (int ct = 0; ct < 4; ++ct)
#pragma unroll
        for (int r = 0; r < 4; ++r)
          outw[1][g * 4 + r][ct * 16 + c16] = ob[ct][r];
    }
    __syncthreads();  // barrier C: all partials ready

    // ---- cross-wave reduce (8 partials, 32 q-rows) + write attn ----
    {
      int q = tid >> 4, dg = (tid & 15) * 4;
      int s = q >> 4, qr = q & 15;
      float v0 = 0.f, v1 = 0.f, v2 = 0.f, v3 = 0.f;
#pragma unroll
      for (int wi = 0; wi < 8; ++wi) {
        const float* op = (const float*)uni[wi] + (size_t)s * 16 * 66 + qr * 66 + dg;
        float4 rd = *(const float4*)op;
        v0 += rd.x; v1 += rd.y; v2 += rd.z; v3 += rd.w;
      }
      s16x4 st;
      st[0] = f2bf(v0); st[1] = f2bf(v1); st[2] = f2bf(v2); st[3] = f2bf(v3);
      *(s16x4*)(attn + ((size_t)(n * TT) + q0 + q) * DD + h * DHD + dg) = st;
    }
    // next head's pbuf writes are fenced by barrier A of that head
  }

  // ---- write probs mean (1/H), vectorized float4 ----
#pragma unroll
  for (int s = 0; s < 2; ++s)
#pragma unroll
    for (int ct = 0; ct < 8; ++ct) {
      float4 o;
      o.x = pm[s][ct][0] * 0.125f; o.y = pm[s][ct][1] * 0.125f;
      o.z = pm[s][ct][2] * 0.125f; o.w = pm[s][ct][3] * 0.125f;
      *(float4*)&pmean[rowbase[s] + ct * 16] = o;
    }
}

extern "C" void kernel_launch(void* const* d_in, const int* in_sizes, int n_in,
                              void* d_out, int out_size, void* d_ws, size_t ws_size,
                              hipStream_t stream) {
  const float* query = (const float*)d_in[0];
  const float* key_  = (const float*)d_in[1];
  const float* value = (const float*)d_in[2];
  const float* segms = (const float*)d_in[3];
  const int*   mask  = (const int*)d_in[4];
  const float* Wq = (const float*)d_in[5];
  const float* bq = (const float*)d_in[6];
  const float* Wk = (const float*)d_in[7];
  const float* bk = (const float*)d_in[8];
  const float* Wv = (const float*)d_in[9];
  const float* bv = (const float*)d_in[10];
  const float* Wo = (const float*)d_in[11];
  const float* bo = (const float*)d_in[12];

  char* ws = (char*)d_ws;
  short* WT   = (short*)(ws);                        // 4 x 512x512 bf16 = 2 MB
  short* qb   = (short*)(ws + ((size_t)2  << 20));   // [N,H,T,64] bf16 = 8 MB
  short* kb   = (short*)(ws + ((size_t)10 << 20));   // [N,H,T,64] bf16 = 8 MB
  short* vT   = (short*)(ws + ((size_t)18 << 20));   // [N,H,64,T] bf16 = 8 MB
  short* attn = (short*)(ws + ((size_t)26 << 20));   // [N,T,D]   bf16 = 8 MB
  float* outp  = (float*)d_out;
  float* pmean = outp + (size_t)NB * TT * DD;

  kt_transpose<<<dim3(16, 16, 4), dim3(32, 8), 0, stream>>>(Wq, Wk, Wv, Wo, WT);
  kt_proj<<<dim3(64, 4, 3), 256, 0, stream>>>(query, key_, value, WT, bq, bk, bv, qb, kb, vT);
  kt_attn<<<dim3(256), dim3(512), 0, stream>>>(qb, kb, vT, segms, mask, attn, pmean);
  kt_outproj<<<dim3(64, 4), 256, 0, stream>>>(attn, WT + (size_t)3 * DD * DD, bo, outp);
}